// Round 2
// baseline (496.192 us; speedup 1.0000x reference)
//
#include <hip/hip_runtime.h>

// LSTM B=32768, T=512, I=2, H=16 — MFMA recurrence v3:
// unit-major tiles + x-proj/bias folded into MFMA spare slots (v2) + ping-pong
// B fragments fixing v2's RAW hazard (per-tile activation wrote Bh/Bl while
// later tiles' MFMA2 still needed the old fragment).
//
// Tile relabel: A-row m of tile t = W row (m&3)*16 + 4t + (m>>2)
// (gate = m&3, out-unit = 4t + (m>>2)). C/D row 4q+j -> gate j, unit 4t+q:
// each lane gets ALL FOUR gate pre-acts of unit 4t+q in acc[t][0..3], so the
// activation chain for tile t starts right after MFMA2[t] and there are 4
// independent activation chains per wave.
// K-axis unit relabel: k-pair p <-> input unit 4*(p&3) + (p>>2); lane q's
// B u32 w holds unit 4w+q == exactly the unit its tile-w activation makes,
// so the C/D==next-B alignment survives with no cross-lane traffic.
//
// MFMA2's odd-k B slots carry the x-projection:
//   B odd slot (lane q) = {x0_hi, x0_lo, x1_hi, x1_lo}[q]  (bf16, per step)
//   A2 odd slots w=0: (W_ih[:,sel]*gsc)_hi, w=1: (W_ih[:,sel]*gsc)_lo
//   -> all 4 split cross terms present, error ~2^-16.
// Bias rides MFMA1's C operand.
//
// Activation per unit (7 trans, minimal): I,F,G,O = exp2(gate');
//   (P1,P2) = (1+I)(1+G),(1+F)(1+O); R = rcp(P1*P2);
//   cs' = R*fma(P1*Op, cs, 2L(G-1)*P2); tanh(c) = 1-2*rcp(1+exp2(cs'));
//   h = (P1*Fp*R)*tanh(c).   [cs = 2*log2e*c domain]

#define T_STEPS 512
#define LOG2E 1.44269504088896340736f

typedef __bf16 bf16x8 __attribute__((ext_vector_type(8)));
typedef float  f32x4  __attribute__((ext_vector_type(4)));
typedef float  f32x2  __attribute__((ext_vector_type(2)));
typedef unsigned int u32x4 __attribute__((ext_vector_type(4)));

union frag_u { u32x4 u; bf16x8 v; };

#if __has_builtin(__builtin_amdgcn_exp2f)
__device__ __forceinline__ float fexp2(float x) { return __builtin_amdgcn_exp2f(x); }
#else
__device__ __forceinline__ float fexp2(float x) { return exp2f(x); }
#endif
#if __has_builtin(__builtin_amdgcn_rcpf)
__device__ __forceinline__ float frcp(float x) { return __builtin_amdgcn_rcpf(x); }
#else
__device__ __forceinline__ float frcp(float x) { return 1.0f / x; }
#endif

// (hi,hi) duplicate of the bf16-truncated value: one v_perm.
__device__ __forceinline__ unsigned dup_hi(float h) {
    unsigned hb = __float_as_uint(h);
#if __has_builtin(__builtin_amdgcn_perm)
    return __builtin_amdgcn_perm(hb, hb, 0x03020302u);
#else
    return (hb >> 16) | (hb & 0xFFFF0000u);
#endif
}
// low16 = bf16(res) of h, high16 = high16 of xq (x part, bf16-in-high16).
__device__ __forceinline__ unsigned lo_with_x(float res, unsigned xq) {
#if __has_builtin(__builtin_amdgcn_perm)
    return __builtin_amdgcn_perm(xq, __float_as_uint(res), 0x07060302u);
#else
    return (__float_as_uint(res) >> 16) | (xq & 0xFFFF0000u);
#endif
}
// setup-only: (hi,lo) k-interleaved pack for the A fragment
__device__ __forceinline__ unsigned pack_hilo(float h) {
    unsigned hb = __float_as_uint(h);
    float    res = h - __uint_as_float(hb & 0xFFFF0000u);
#if __has_builtin(__builtin_amdgcn_perm)
    return __builtin_amdgcn_perm(__float_as_uint(res), hb, 0x07060302u);
#else
    return (hb >> 16) | (__float_as_uint(res) & 0xFFFF0000u);
#endif
}
// bf16 (truncated) of v, placed in HIGH 16 bits, low16 zero.
__device__ __forceinline__ unsigned bfhi(float v) {
    return __float_as_uint(v) & 0xFFFF0000u;
}
// x part for this lane's q: col = q>=2, part (hi/lo) = q&1; bf16 in high16.
__device__ __forceinline__ unsigned make_xq(float nx0, float nx1, int q) {
    const float xs = (q & 2) ? nx1 : nx0;
    const unsigned h16 = bfhi(xs);
    const unsigned l16 = bfhi(xs - __uint_as_float(h16));
    return (q & 1) ? l16 : h16;
}

// One LSTM step: reads (BhI, BlI), writes (BhO, BlO). Ping-pong caller-side.
__device__ __forceinline__ void lstm_step(
    const frag_u& BhI, const frag_u& BlI,
    frag_u& BhO, frag_u& BlO,
    float cs[4],
    const frag_u A1[4], const frag_u A2[4], const f32x4 biasf[4],
    unsigned xqn)
{
    f32x4 acc[4];
    #pragma unroll
    for (int t = 0; t < 4; ++t)
        acc[t] = __builtin_amdgcn_mfma_f32_16x16x32_bf16(A1[t].v, BhI.v, biasf[t], 0, 0, 0);

    #pragma unroll
    for (int t = 0; t < 4; ++t) {
        acc[t] = __builtin_amdgcn_mfma_f32_16x16x32_bf16(A2[t].v, BlI.v, acc[t], 0, 0, 0);

        f32x2 eIF, eGO;
        eIF.x = fexp2(acc[t][0]);          // I
        eIF.y = fexp2(acc[t][1]);          // F
        eGO.x = fexp2(acc[t][2]);          // G
        eGO.y = fexp2(acc[t][3]);          // O
        const f32x2 pA = eIF + 1.0f;       // (Ip, Fp)
        const f32x2 pB = eGO + 1.0f;       // (Gp, Op)
        const f32x2 PP = pA * pB;          // (P1, P2)
        const float R  = frcp(PP.x * PP.y);
        const float Gm = fmaf(2.0f * LOG2E, eGO.x, -2.0f * LOG2E); // 2L(G-1)
        const float u1 = fmaf(PP.x * pB.y, cs[t], Gm * PP.y);
        const float csn = u1 * R;          // cs' = sf*cs + 2L*si*tg
        cs[t] = csn;
        const float C2 = fexp2(csn);
        const float tc = fmaf(-2.0f, frcp(C2 + 1.0f), 1.0f);  // tanh(c)
        const float hn = (PP.x * pA.y) * R * tc;              // so*tanh(c)

        const unsigned hb = __float_as_uint(hn);
        BhO.u[t] = dup_hi(hn);
        const float resf = hn - __uint_as_float(hb & 0xFFFF0000u);
        BlO.u[t] = lo_with_x(resf, xqn);
    }
}

__global__ __launch_bounds__(256, 2)
void lstm_mfma_kernel(const float* __restrict__ x,
                      const float* __restrict__ W_ih,
                      const float* __restrict__ W_hh,
                      const float* __restrict__ b_ih,
                      const float* __restrict__ b_hh,
                      const float* __restrict__ W1,
                      const float* __restrict__ b1,
                      const float* __restrict__ W2,
                      const float* __restrict__ b2,
                      float* __restrict__ out)
{
    __shared__ float hsm[4][16][16];   // head only; per-wave private, no barriers

    const int tid  = threadIdx.x;
    const int wv   = tid >> 6;
    const int lane = tid & 63;
    const int e    = lane & 15;        // elem within wave (C/D col, B col)
    const int q    = lane >> 4;        // quad (C/D row block, A/B k block)
    const int m    = lane & 15;        // A row within tile

    // per-gate exp2-argument scales (gate order i,f,g,o along m&3)
    const float gsc[4] = { -LOG2E, -LOG2E, 2.0f * LOG2E, -LOG2E };

    // ---- static fragments ---------------------------------------------------
    // A1[t]: W_hh, rows (gate=m&3, unit 4t+(m>>2)), k-pair w -> in-unit 4w+q,
    //        (hi,lo) interleaved split-bf16 of the gsc-scaled weight.
    // A2[t]: even k = W_hi (pairs h_lo), odd k of u[0],u[1] = x-weight split.
    // biasf[t][j]: (b_ih+b_hh)*gsc at row gate j, unit 4t+q  (MFMA1 C operand).
    frag_u A1[4], A2[4];
    f32x4  biasf[4];
    #pragma unroll
    for (int t = 0; t < 4; ++t) {
        const int   g  = m & 3;
        const int   Rr = g * 16 + 4 * t + (m >> 2);
        const float sc = gsc[g];

        const float xw0 = W_ih[Rr * 2 + 0] * sc;
        const float xw1 = W_ih[Rr * 2 + 1] * sc;
        const unsigned x0h = bfhi(xw0);
        const unsigned x0l = bfhi(xw0 - __uint_as_float(x0h));
        const unsigned x1h = bfhi(xw1);
        const unsigned x1l = bfhi(xw1 - __uint_as_float(x1h));
        // lane q's B odd slot carries {x0_hi,x0_lo,x1_hi,x1_lo}[q]; the A2 odd
        // coefficient must be the matching W_ih part:
        const unsigned cw0 = (q < 2) ? x0h : x1h;   // w=0: hi coefficient
        const unsigned cw1 = (q < 2) ? x0l : x1l;   // w=1: lo coefficient

        #pragma unroll
        for (int w = 0; w < 4; ++w) {
            const float whh = W_hh[Rr * 16 + 4 * w + q] * sc;
            A1[t].u[w] = pack_hilo(whh);
            A2[t].u[w] = __float_as_uint(whh) >> 16;   // even k: W_hi, odd k: 0
        }
        A2[t].u[0] |= cw0;
        A2[t].u[1] |= cw1;

        #pragma unroll
        for (int j = 0; j < 4; ++j) {
            const int Rb = j * 16 + 4 * t + q;
            biasf[t][j] = (b_ih[Rb] + b_hh[Rb]) * gsc[j];
        }
    }

    const int gelem = blockIdx.x * 64 + wv * 16 + e;
    const float4* xp = (const float4*)(x + (size_t)gelem * (T_STEPS * 2));

    frag_u BhA, BlA, BhB, BlB;             // ping-pong h fragments
    float  cs[4] = {0.f, 0.f, 0.f, 0.f};   // c in 2log2e domain, unit 4t+q

    float4 xv = xp[0];

    // prologue: BhA = 0 (h_-1 = 0); BlA odd slots = x for step 0, low16 = 0.
    {
        const unsigned xq0 = make_xq(xv.x, xv.y, q);
        #pragma unroll
        for (int w = 0; w < 4; ++w) { BhA.u[w] = 0u; BlA.u[w] = xq0; }
    }

    for (int t2 = 0; t2 < T_STEPS / 2; ++t2) {
        const float4 xnext = xp[(t2 + 1) & (T_STEPS / 2 - 1)];

        // x parts for steps s0+1 and s0+2 (independent: fill MFMA shadow)
        const unsigned xq1 = make_xq(xv.z, xv.w, q);
        const unsigned xq2 = make_xq(xnext.x, xnext.y, q);

        lstm_step(BhA, BlA, BhB, BlB, cs, A1, A2, biasf, xq1);  // step s0
        lstm_step(BhB, BlB, BhA, BlA, cs, A1, A2, biasf, xq2);  // step s0+1

        xv = xnext;
    }

    // ---- MLP head: z = tanh(W1 h + b1); y = W2 z + b2. Intra-wave, no barrier.
    #pragma unroll
    for (int r = 0; r < 4; ++r) {
        const float hval = __uint_as_float(BhA.u[r] << 16) +   // hi part
                           __uint_as_float(BlA.u[r] << 16);    // lo part (x bits drop)
        hsm[wv][e][4 * r + q] = hval;                          // unit 4r+q
    }

    float hv[16];
    #pragma unroll
    for (int j = 0; j < 4; ++j) {
        const float4 t4 = *(const float4*)&hsm[wv][e][4 * j];
        hv[4 * j + 0] = t4.x; hv[4 * j + 1] = t4.y;
        hv[4 * j + 2] = t4.z; hv[4 * j + 3] = t4.w;
    }

    float z[4];
    #pragma unroll
    for (int r = 0; r < 4; ++r) {
        const int mm = 4 * q + r;
        float a = b1[mm];
        #pragma unroll
        for (int j = 0; j < 16; ++j) a = fmaf(W1[mm * 16 + j], hv[j], a);
        const float E = fexp2(a * (2.0f * LOG2E));
        z[r] = fmaf(-2.0f, frcp(1.0f + E), 1.0f);   // safe at +-inf
    }
    #pragma unroll
    for (int r = 0; r < 4; ++r) hsm[wv][e][4 * q + r] = z[r];

    if (q < 2) {
        float a = b2[q];
        #pragma unroll
        for (int j = 0; j < 16; ++j) a = fmaf(W2[q * 16 + j], hsm[wv][e][j], a);
        out[(size_t)gelem * 2 + q] = a;
    }
}

extern "C" void kernel_launch(void* const* d_in, const int* in_sizes, int n_in,
                              void* d_out, int out_size, void* d_ws, size_t ws_size,
                              hipStream_t stream) {
    const float* x    = (const float*)d_in[0];
    const float* W_ih = (const float*)d_in[1];
    const float* W_hh = (const float*)d_in[2];
    const float* b_ih = (const float*)d_in[3];
    const float* b_hh = (const float*)d_in[4];
    const float* W1   = (const float*)d_in[5];
    const float* b1   = (const float*)d_in[6];
    const float* W2   = (const float*)d_in[7];
    const float* b2   = (const float*)d_in[8];
    float* out = (float*)d_out;

    // 32768 elems / 64 per block (4 waves x 16) = 512 blocks
    lstm_mfma_kernel<<<dim3(512), dim3(256), 0, stream>>>(
        x, W_ih, W_hh, b_ih, b_hh, W1, b1, W2, b2, out);
}